// Round 19
// baseline (196.491 us; speedup 1.0000x reference)
//
#include <hip/hip_runtime.h>
#include <hip/hip_bf16.h>
#include <stdint.h>

// Problem constants
#define MB 8192     // batch (rows and cols of sim)
#define KD 256      // embedding dim
#define BM 128      // rows per block (4 waves x 32 rows)
#define NSPLIT 8    // column slabs (512 blocks: proven-good L2 behavior)
#define SLAB (MB / NSPLIT)   // 1024 cols per slab
#define NCT (SLAB / 16)      // 64 col-tiles of 16 per slab
#define VOCAB 1000000
#define COFF 104.0f          // fixed exp offset (overflow/underflow-safe)
#define LOG2E 1.44269504088896340736f

typedef __attribute__((ext_vector_type(8))) short bf16x8;
typedef __attribute__((ext_vector_type(4))) float f32x4;

__device__ __forceinline__ unsigned short f2bf(float x) {
  union { float f; uint32_t u; } v; v.f = x;
  uint32_t r = v.u + 0x7fffu + ((v.u >> 16) & 1u);   // RNE
  return (unsigned short)(r >> 16);
}

__device__ __forceinline__ float fast_exp2(float x) {
#if __has_builtin(__builtin_amdgcn_exp2f)
  return __builtin_amdgcn_exp2f(x);
#else
  return exp2f(x);
#endif
}

// ---- convert fp32->bf16 for A,B + pos_sim (fp32, wave per row) + zero hist ----
__global__ __launch_bounds__(256) void convertpos_kernel(
    const float* __restrict__ A, const float* __restrict__ B,
    unsigned short* __restrict__ Abf, unsigned short* __restrict__ Bbf,
    float* __restrict__ pos, int* __restrict__ hist) {
  int t = blockIdx.x * 256 + threadIdx.x;        // 524288 threads, 1 float4 each
  const float4 a = ((const float4*)A)[t];
  const float4 b = ((const float4*)B)[t];
  ushort4 oa, ob;
  oa.x = f2bf(a.x); oa.y = f2bf(a.y); oa.z = f2bf(a.z); oa.w = f2bf(a.w);
  ob.x = f2bf(b.x); ob.y = f2bf(b.y); ob.z = f2bf(b.z); ob.w = f2bf(b.w);
  ((ushort4*)Abf)[t] = oa;
  ((ushort4*)Bbf)[t] = ob;
  // pos_sim: wave (t>>6) == row, 64 lanes cover KD/4 float4 chunks
  float d = a.x * b.x + a.y * b.y + a.z * b.z + a.w * b.w;
  #pragma unroll
  for (int off = 32; off; off >>= 1) d += __shfl_down(d, off, 64);
  if ((threadIdx.x & 63) == 0) pos[t >> 6] = d;
  // zero the vocab histogram (1M ints == 524288 uint2)
  ((uint2*)hist)[t] = make_uint2(0u, 0u);
}

// ---- histogram of ids + b2 = -(log2 q + C*log2e) + zero accumulators ----
__global__ __launch_bounds__(256) void histb2_kernel(
    const int* __restrict__ ids, const float* __restrict__ q,
    int* __restrict__ hist, float* __restrict__ b2,
    float* __restrict__ ps, float* __restrict__ out) {
  int i = blockIdx.x * 256 + threadIdx.x;   // 32 blocks -> 8192 threads
  atomicAdd(&hist[ids[i]], 1);
  // exp(sim - ln q - C) == exp2(sim*LOG2E + b2), b2 = -(log2 q + C*LOG2E)
  b2[i] = -(log2f(q[i]) + COFF * LOG2E);
  ps[i] = 0.0f;
  if (i == 0) out[0] = 0.0f;
}

// ---- fused GEMM + masked fixed-offset exp-sum, NO LDS / NO BARRIERS ----
// The B slab panel (1024 cols x 256 k x 2B = 512 KB) is L2-resident and shared
// by the 64 blocks of the slab, so each wave loads its B fragments DIRECTLY
// from L2 per 16-col tile (16B/lane, 16 dense 64B lines per instruction --
// same gather shape as the afrag prologue). Removes all LDS staging, DMAs,
// vmcnt drains and __syncthreads. Latency hidden by register double-buffering
// (tile ct+1 prefetched into the other named state) + 2 waves/SIMD.
__global__ __launch_bounds__(256) void fused_kernel(
    const unsigned short* __restrict__ Abf,
    const unsigned short* __restrict__ Bbf,
    const int* __restrict__ ids,
    const float* __restrict__ b2,
    float* __restrict__ ps) {
  const int slab = blockIdx.y;
  const int tid = threadIdx.x;
  const int wave = tid >> 6;
  const int lane = tid & 63;
  const int quad = lane >> 4;
  const int lpos = lane & 15;
  const int rowbase = blockIdx.x * BM + wave * 32;
  const int colbase = slab * SLAB;

  // A fragments resident: wave owns rows [rowbase, rowbase+32)  (64 VGPRs)
  bf16x8 afrag[2][8];
  #pragma unroll
  for (int rt = 0; rt < 2; ++rt)
    #pragma unroll
    for (int kb = 0; kb < 8; ++kb)
      afrag[rt][kb] = *(const bf16x8*)(Abf + (rowbase + rt * 16 + lpos) * KD + kb * 32 + quad * 8);

  int idr[2][4];
  float srun[2][4];
  #pragma unroll
  for (int rt = 0; rt < 2; ++rt)
    #pragma unroll
    for (int r = 0; r < 4; ++r) {
      idr[rt][r] = ids[rowbase + rt * 16 + quad * 4 + r];
      srun[rt][r] = 0.0f;
    }

  // lane-fixed B base: col = (colbase + ct*16 + lpos), k-offset = quad*8
  const unsigned short* bbase = Bbf + (size_t)(colbase + lpos) * KD + quad * 8;

  // Two named prefetch states (static indexing -- rule #20: no runtime-indexed
  // register arrays). LOADB issues next tile's loads; COMPUTE consumes one.
  int idA, idB;
  float bA, bB;
  bf16x8 bfA[8], bfB[8];

#define LOADB(CT, S)                                                           \
  {                                                                            \
    const int c0 = (CT) * 16;                                                  \
    id##S = ids[colbase + c0 + lpos];                                          \
    b##S  = b2 [colbase + c0 + lpos];                                          \
    const unsigned short* bp = bbase + (size_t)c0 * KD;                        \
    _Pragma("unroll")                                                          \
    for (int kb = 0; kb < 8; ++kb)                                             \
      bf##S[kb] = *(const bf16x8*)(bp + kb * 32);                              \
  }

#define COMPUTE(S)                                                             \
  {                                                                            \
    _Pragma("unroll")                                                          \
    for (int rt = 0; rt < 2; ++rt) {                                           \
      f32x4 acc = {0.0f, 0.0f, 0.0f, 0.0f};                                    \
      _Pragma("unroll")                                                        \
      for (int kb = 0; kb < 8; ++kb)                                           \
        acc = __builtin_amdgcn_mfma_f32_16x16x32_bf16(afrag[rt][kb], bf##S[kb], acc, 0, 0, 0); \
      _Pragma("unroll")                                                        \
      for (int r = 0; r < 4; ++r) {                                            \
        const float e = fast_exp2(__builtin_fmaf(acc[r], LOG2E, b##S));        \
        srun[rt][r] += (id##S != idr[rt][r]) ? e : 0.0f;                       \
      }                                                                        \
    }                                                                          \
  }

  LOADB(0, A)
  for (int ct2 = 0; ct2 < NCT; ct2 += 2) {
    LOADB(ct2 + 1, B)                    // NCT even: ct2+1 <= NCT-1 always
    COMPUTE(A)
    if (ct2 + 2 < NCT) LOADB(ct2 + 2, A)
    COMPUTE(B)
  }
#undef LOADB
#undef COMPUTE

  // sum across the 16 lanes of each quad (the 16 columns of the frag)
  #pragma unroll
  for (int rt = 0; rt < 2; ++rt)
    #pragma unroll
    for (int r = 0; r < 4; ++r) {
      float v = srun[rt][r];
      #pragma unroll
      for (int off = 1; off < 16; off <<= 1) v += __shfl_xor(v, off, 64);
      if (lpos == 0)
        atomicAdd(&ps[rowbase + rt * 16 + quad * 4 + r], v);
    }
}

// ---- finalize: per-row loss, mean ----
__global__ __launch_bounds__(256) void finalize_kernel(
    const float* __restrict__ ps, const float* __restrict__ pos,
    const float* __restrict__ q, const int* __restrict__ ids,
    const int* __restrict__ hist, float* __restrict__ out) {
  int i = blockIdx.x * 256 + threadIdx.x;   // 32 blocks -> 8192 threads
  const float s = ps[i];
  const float nm = (float)(MB - hist[ids[i]]);
  // log S_i = log(s) + C + log(1-q_i) - log(n_miss)
  const float z = logf(s) + COFF + logf(1.0f - q[i]) - logf(nm);
  const float p = pos[i];
  const float hi = fmaxf(p, z), lo = fminf(p, z);
  float loss = -p + hi + log1pf(__expf(lo - hi));

  #pragma unroll
  for (int off = 32; off; off >>= 1) loss += __shfl_down(loss, off, 64);
  __shared__ float red[4];
  if ((threadIdx.x & 63) == 0) red[threadIdx.x >> 6] = loss;
  __syncthreads();
  if (threadIdx.x == 0) {
    float t = red[0] + red[1] + red[2] + red[3];
    atomicAdd(out, t * (1.0f / (float)MB));
  }
}

extern "C" void kernel_launch(void* const* d_in, const int* in_sizes, int n_in,
                              void* d_out, int out_size, void* d_ws, size_t ws_size,
                              hipStream_t stream) {
  (void)in_sizes; (void)n_in; (void)out_size; (void)ws_size;
  const float* input_emb  = (const float*)d_in[0];
  const float* target_emb = (const float*)d_in[1];
  const int*   target_ids = (const int*)d_in[2];
  const float* q_probas   = (const float*)d_in[3];
  float* out = (float*)d_out;

  char* ws = (char*)d_ws;
  unsigned short* Abf = (unsigned short*)(ws);                    // 4 MB
  unsigned short* Bbf = (unsigned short*)(ws + (4u << 20));       // 4 MB
  int*   hist = (int*)  (ws + (8u << 20));                        // 4 MB
  float* b2   = (float*)(ws + (12u << 20));                       // 32 KB
  float* pos  = (float*)(ws + (12u << 20) + 32768);               // 32 KB
  float* ps   = (float*)(ws + (12u << 20) + 65536);               // 32 KB

  convertpos_kernel<<<2048, 256, 0, stream>>>(input_emb, target_emb, Abf, Bbf, pos, hist);
  histb2_kernel<<<32, 256, 0, stream>>>(target_ids, q_probas, hist, b2, ps, out);
  fused_kernel<<<dim3(MB / BM, NSPLIT), 256, 0, stream>>>(Abf, Bbf, target_ids, b2, ps);
  finalize_kernel<<<32, 256, 0, stream>>>(ps, pos, q_probas, target_ids, hist, out);
}

// Round 20
// 130.864 us; speedup vs baseline: 1.5015x; 1.5015x over previous
//
#include <hip/hip_runtime.h>
#include <hip/hip_bf16.h>
#include <stdint.h>

// Problem constants
#define MB 8192     // batch (rows and cols of sim)
#define KD 256      // embedding dim
#define BM 128      // rows per block (8 waves, 4x2: each 32 rows x 32 cols)
#define BN 64       // cols per chunk
#define NSPLIT 8    // column slabs (512 blocks: proven-good L2 behavior)
#define SLAB (MB / NSPLIT)   // 1024 cols per slab
#define NCHUNK (SLAB / BN)   // 16 chunks per slab
#define VOCAB 1000000
#define COFF 104.0f          // fixed exp offset (overflow/underflow-safe)
#define LOG2E 1.44269504088896340736f

typedef __attribute__((ext_vector_type(8))) short bf16x8;
typedef __attribute__((ext_vector_type(4))) float f32x4;

__device__ __forceinline__ unsigned short f2bf(float x) {
  union { float f; uint32_t u; } v; v.f = x;
  uint32_t r = v.u + 0x7fffu + ((v.u >> 16) & 1u);   // RNE
  return (unsigned short)(r >> 16);
}

__device__ __forceinline__ float fast_exp2(float x) {
#if __has_builtin(__builtin_amdgcn_exp2f)
  return __builtin_amdgcn_exp2f(x);
#else
  return exp2f(x);
#endif
}

// async global->LDS DMA, 16B per lane, LDS dest = wave-uniform base + lane*16
#define GLOAD_LDS16(g, l)                                                      \
  __builtin_amdgcn_global_load_lds(                                            \
      (const __attribute__((address_space(1))) void*)(g),                      \
      (__attribute__((address_space(3))) void*)(l), 16, 0, 0)

// ---- convert fp32->bf16 for A,B + pos_sim (fp32, wave per row) + zero hist ----
__global__ __launch_bounds__(256) void convertpos_kernel(
    const float* __restrict__ A, const float* __restrict__ B,
    unsigned short* __restrict__ Abf, unsigned short* __restrict__ Bbf,
    float* __restrict__ pos, int* __restrict__ hist) {
  int t = blockIdx.x * 256 + threadIdx.x;        // 524288 threads, 1 float4 each
  const float4 a = ((const float4*)A)[t];
  const float4 b = ((const float4*)B)[t];
  ushort4 oa, ob;
  oa.x = f2bf(a.x); oa.y = f2bf(a.y); oa.z = f2bf(a.z); oa.w = f2bf(a.w);
  ob.x = f2bf(b.x); ob.y = f2bf(b.y); ob.z = f2bf(b.z); ob.w = f2bf(b.w);
  ((ushort4*)Abf)[t] = oa;
  ((ushort4*)Bbf)[t] = ob;
  // pos_sim: wave (t>>6) == row, 64 lanes cover KD/4 float4 chunks
  float d = a.x * b.x + a.y * b.y + a.z * b.z + a.w * b.w;
  #pragma unroll
  for (int off = 32; off; off >>= 1) d += __shfl_down(d, off, 64);
  if ((threadIdx.x & 63) == 0) pos[t >> 6] = d;
  // zero the vocab histogram (1M ints == 524288 uint2)
  ((uint2*)hist)[t] = make_uint2(0u, 0u);
}

// ---- histogram of ids + b2 = -(log2 q + C*log2e) + zero accumulators ----
__global__ __launch_bounds__(256) void histb2_kernel(
    const int* __restrict__ ids, const float* __restrict__ q,
    int* __restrict__ hist, float* __restrict__ b2,
    float* __restrict__ ps, float* __restrict__ out) {
  int i = blockIdx.x * 256 + threadIdx.x;   // 32 blocks -> 8192 threads
  atomicAdd(&hist[ids[i]], 1);
  // exp(sim - ln q - C) == exp2(sim*LOG2E + b2), b2 = -(log2 q + C*LOG2E)
  b2[i] = -(log2f(q[i]) + COFF * LOG2E);
  ps[i] = 0.0f;
  if (i == 0) out[0] = 0.0f;
}

// ---- fused GEMM + masked fixed-offset exp-sum, 2-phase dbuf, 512 threads ----
// R6's exact memory structure (512 blocks, BM=128, BN=64, 32KB dbuf, 16 chunks)
// but 8 waves/block (4x2 tile: wave owns 32 rows x 32 cols). Per-block LDS/MFMA/
// VALU streams per chunk identical to R6; resident waves/CU double (8 -> 16,
// 4/SIMD) to fill the latency bubbles. ids/b2 in LDS tables (R15-proven) keeps
// compute phase vmem-free and VGPRs ~110. No min-waves launch-bounds arg (R16).
__global__ __launch_bounds__(512) void fused_kernel(
    const unsigned short* __restrict__ Abf,
    const unsigned short* __restrict__ Bbf,
    const int* __restrict__ ids,
    const float* __restrict__ b2,
    float* __restrict__ ps) {
  const int slab = blockIdx.y;
  const int tid = threadIdx.x;
  const int wave = tid >> 6;
  const int wr = wave >> 1;                  // wave row-tile (0..3): 32 rows
  const int wc = wave & 1;                   // wave col-tile (0..1): 32 cols
  const int lane = tid & 63;
  const int quad = lane >> 4;
  const int lpos = lane & 15;
  const int rowbase = blockIdx.x * BM + wr * 32;
  const int colbase = slab * SLAB;

  // Fragment-ordered B staging, DOUBLE buffered: cell c = ((ct*8+kb)*4+qd)*16+lp
  // holds B[col = ct*16+lp][k = kb*32+qd*8 .. +8), ct<4. With 512 threads,
  // c == tid + s8*512 (s8 < 4) decomposes to ct=s8, kb=(tid>>6)&7, qd=(tid>>4)&3,
  // lp=tid&15 -> linear LDS dest matches global_load_lds uniform-base+lane*16.
  // Wave (wr,wc) reads only ct pair {wc*2, wc*2+1}: 16 ds_read_b128/chunk.
  __shared__ unsigned short Bs[2][2048 * 8];   // 2 x 32 KB = 64 KB
  __shared__ int   ids_s[SLAB];                // 4 KB (slab-constant)
  __shared__ float b2_s[SLAB];                 // 4 KB (slab-constant)

  // slab tables: 1024 entries, 2 per thread, coalesced 8B loads
  const int2   tiv = ((const int2*)(ids + colbase))[tid];
  const float2 tbv = ((const float2*)(b2 + colbase))[tid];

  // A fragments resident: wave owns rows [rowbase, rowbase+32)  (64 VGPRs)
  bf16x8 afrag[2][8];
  #pragma unroll
  for (int rt = 0; rt < 2; ++rt)
    #pragma unroll
    for (int kb = 0; kb < 8; ++kb)
      afrag[rt][kb] = *(const bf16x8*)(Abf + (rowbase + rt * 16 + lpos) * KD + kb * 32 + quad * 8);

  // Affine staging addresses (c = tid + s8*512, s8 < 4 -> ct = s8):
  //   global off = gbase + s8*16*KD + chunk*BN*KD     [shorts]
  //   LDS off    = tid*8 + s8*4096                    [shorts]
  const unsigned short* gbase =
      Bbf + (colbase + (tid & 15)) * KD + ((tid >> 6) & 7) * 32 + ((tid >> 4) & 3) * 8;

#define STAGE(T, BUF)                                                          \
  _Pragma("unroll")                                                            \
  for (int s8 = 0; s8 < 4; ++s8)                                               \
    GLOAD_LDS16(gbase + (T) * (BN * KD) + s8 * (16 * KD),                      \
                &Bs[BUF][0] + tid * 8 + s8 * 4096);

  int idr[2][4];
  float srun[2][4];
  #pragma unroll
  for (int rt = 0; rt < 2; ++rt)
    #pragma unroll
    for (int r = 0; r < 4; ++r) {
      idr[rt][r] = ids[rowbase + rt * 16 + quad * 4 + r];
      srun[rt][r] = 0.0f;
    }

  // Prologue: stage chunk 0, park slab tables in LDS, barrier (drains vmcnt).
  STAGE(0, 0)
  ((int2*)ids_s)[tid] = tiv;
  ((float2*)b2_s)[tid] = tbv;
  __syncthreads();                           // chunk 0 + tables ready

  // Per iteration: issue next-chunk DMA first, then compute current chunk from
  // registers+LDS only (tables are LDS -> lgkmcnt, independent of DMA vmcnt).
  // End-of-body __syncthreads() drains the prefetch, hidden under MFMA+exp.
#define FUSED_BODY(T, CUR)                                                     \
  {                                                                            \
    if ((T) + 1 < NCHUNK) { STAGE((T) + 1, (CUR) ^ 1) }                        \
    _Pragma("unroll")                                                          \
    for (int ctl = 0; ctl < 2; ++ctl) {                                        \
      const int ct = wc * 2 + ctl;                                             \
      const int jloc = (T) * BN + ct * 16 + lpos;                              \
      const int idj = ids_s[jloc];                                             \
      const float bj = b2_s[jloc];                                             \
      const unsigned short* bp = &Bs[CUR][0] + (ct * 512 + quad * 16 + lpos) * 8; \
      bf16x8 bfrag[8];                                                         \
      _Pragma("unroll")                                                        \
      for (int kb = 0; kb < 8; ++kb)                                           \
        bfrag[kb] = *(const bf16x8*)(bp + kb * 512);                           \
      _Pragma("unroll")                                                        \
      for (int rt = 0; rt < 2; ++rt) {                                         \
        f32x4 acc = {0.0f, 0.0f, 0.0f, 0.0f};                                  \
        _Pragma("unroll")                                                      \
        for (int kb = 0; kb < 8; ++kb)                                         \
          acc = __builtin_amdgcn_mfma_f32_16x16x32_bf16(afrag[rt][kb], bfrag[kb], acc, 0, 0, 0); \
        _Pragma("unroll")                                                      \
        for (int r = 0; r < 4; ++r) {                                          \
          const float e = fast_exp2(__builtin_fmaf(acc[r], LOG2E, bj));        \
          srun[rt][r] += (idj != idr[rt][r]) ? e : 0.0f;                       \
        }                                                                      \
      }                                                                        \
    }                                                                          \
    __syncthreads();                                                           \
  }

  for (int t2 = 0; t2 < NCHUNK; t2 += 2) {
    FUSED_BODY(t2, 0)
    FUSED_BODY(t2 + 1, 1)
  }
#undef FUSED_BODY
#undef STAGE

  // sum across the 16 lanes of each quad (the 16 columns of the frag).
  // Waves (wr,0)/(wr,1) cover different cols of the same rows -> 2 atomics/row.
  #pragma unroll
  for (int rt = 0; rt < 2; ++rt)
    #pragma unroll
    for (int r = 0; r < 4; ++r) {
      float v = srun[rt][r];
      #pragma unroll
      for (int off = 1; off < 16; off <<= 1) v += __shfl_xor(v, off, 64);
      if (lpos == 0)
        atomicAdd(&ps[rowbase + rt * 16 + quad * 4 + r], v);
    }
}

// ---- finalize: per-row loss, mean ----
__global__ __launch_bounds__(256) void finalize_kernel(
    const float* __restrict__ ps, const float* __restrict__ pos,
    const float* __restrict__ q, const int* __restrict__ ids,
    const int* __restrict__ hist, float* __restrict__ out) {
  int i = blockIdx.x * 256 + threadIdx.x;   // 32 blocks -> 8192 threads
  const float s = ps[i];
  const float nm = (float)(MB - hist[ids[i]]);
  // log S_i = log(s) + C + log(1-q_i) - log(n_miss)
  const float z = logf(s) + COFF + logf(1.0f - q[i]) - logf(nm);
  const float p = pos[i];
  const float hi = fmaxf(p, z), lo = fminf(p, z);
  float loss = -p + hi + log1pf(__expf(lo - hi));

  #pragma unroll
  for (int off = 32; off; off >>= 1) loss += __shfl_down(loss, off, 64);
  __shared__ float red[4];
  if ((threadIdx.x & 63) == 0) red[threadIdx.x >> 6] = loss;
  __syncthreads();
  if (threadIdx.x == 0) {
    float t = red[0] + red[1] + red[2] + red[3];
    atomicAdd(out, t * (1.0f / (float)MB));
  }
}

extern "C" void kernel_launch(void* const* d_in, const int* in_sizes, int n_in,
                              void* d_out, int out_size, void* d_ws, size_t ws_size,
                              hipStream_t stream) {
  (void)in_sizes; (void)n_in; (void)out_size; (void)ws_size;
  const float* input_emb  = (const float*)d_in[0];
  const float* target_emb = (const float*)d_in[1];
  const int*   target_ids = (const int*)d_in[2];
  const float* q_probas   = (const float*)d_in[3];
  float* out = (float*)d_out;

  char* ws = (char*)d_ws;
  unsigned short* Abf = (unsigned short*)(ws);                    // 4 MB
  unsigned short* Bbf = (unsigned short*)(ws + (4u << 20));       // 4 MB
  int*   hist = (int*)  (ws + (8u << 20));                        // 4 MB
  float* b2   = (float*)(ws + (12u << 20));                       // 32 KB
  float* pos  = (float*)(ws + (12u << 20) + 32768);               // 32 KB
  float* ps   = (float*)(ws + (12u << 20) + 65536);               // 32 KB

  convertpos_kernel<<<2048, 256, 0, stream>>>(input_emb, target_emb, Abf, Bbf, pos, hist);
  histb2_kernel<<<32, 256, 0, stream>>>(target_ids, q_probas, hist, b2, ps, out);
  fused_kernel<<<dim3(MB / BM, NSPLIT), 512, 0, stream>>>(Abf, Bbf, target_ids, b2, ps);
  finalize_kernel<<<32, 256, 0, stream>>>(ps, pos, q_probas, target_ids, hist, out);
}

// Round 21
// 119.775 us; speedup vs baseline: 1.6405x; 1.0926x over previous
//
#include <hip/hip_runtime.h>
#include <hip/hip_bf16.h>
#include <stdint.h>

// Problem constants
#define MB 8192     // batch (rows and cols of sim)
#define KD 256      // embedding dim
#define BM 128      // rows per block (4 waves x 32 rows)
#define BN 64       // cols per chunk
#define NSPLIT 8    // column slabs (512 blocks: proven-good L2 behavior)
#define SLAB (MB / NSPLIT)   // 1024 cols per slab
#define NCHUNK (SLAB / BN)   // 16 chunks per slab
#define COFF 104.0f          // fixed exp offset (overflow/underflow-safe)
#define LOG2E 1.44269504088896340736f

typedef __attribute__((ext_vector_type(8))) short bf16x8;
typedef __attribute__((ext_vector_type(4))) float f32x4;

__device__ __forceinline__ unsigned short f2bf(float x) {
  union { float f; uint32_t u; } v; v.f = x;
  uint32_t r = v.u + 0x7fffu + ((v.u >> 16) & 1u);   // RNE
  return (unsigned short)(r >> 16);
}

__device__ __forceinline__ float fast_exp2(float x) {
#if __has_builtin(__builtin_amdgcn_exp2f)
  return __builtin_amdgcn_exp2f(x);
#else
  return exp2f(x);
#endif
}

// async global->LDS DMA, 16B per lane, LDS dest = wave-uniform base + lane*16
#define GLOAD_LDS16(g, l)                                                      \
  __builtin_amdgcn_global_load_lds(                                            \
      (const __attribute__((address_space(1))) void*)(g),                      \
      (__attribute__((address_space(3))) void*)(l), 16, 0, 0)

// ---- prep: fp32->bf16 for A,B + pos_sim + b2 + zero ps/cnt/out ----
// NO histogram: per-row id-match counts are accumulated inside fused_kernel
// (it visits every (i,j) pair exactly once), so the 1M-entry hist, its 4MB
// zeroing and histb2's random atomics are all deleted. histb2's remaining
// work (b2 from q, accumulator zeroing) folds in here: 3 kernels total.
__global__ __launch_bounds__(256) void prep_kernel(
    const float* __restrict__ A, const float* __restrict__ B,
    const float* __restrict__ q,
    unsigned short* __restrict__ Abf, unsigned short* __restrict__ Bbf,
    float* __restrict__ pos, float* __restrict__ b2,
    float* __restrict__ ps, float* __restrict__ cnt,
    float* __restrict__ out) {
  int t = blockIdx.x * 256 + threadIdx.x;        // 524288 threads, 1 float4 each
  const float4 a = ((const float4*)A)[t];
  const float4 b = ((const float4*)B)[t];
  ushort4 oa, ob;
  oa.x = f2bf(a.x); oa.y = f2bf(a.y); oa.z = f2bf(a.z); oa.w = f2bf(a.w);
  ob.x = f2bf(b.x); ob.y = f2bf(b.y); ob.z = f2bf(b.z); ob.w = f2bf(b.w);
  ((ushort4*)Abf)[t] = oa;
  ((ushort4*)Bbf)[t] = ob;
  // pos_sim: wave (t>>6) == row, 64 lanes cover KD/4 float4 chunks
  float d = a.x * b.x + a.y * b.y + a.z * b.z + a.w * b.w;
  #pragma unroll
  for (int off = 32; off; off >>= 1) d += __shfl_down(d, off, 64);
  if ((threadIdx.x & 63) == 0) pos[t >> 6] = d;
  // per-row setup (blocks 0..31): b2 = -(log2 q + C*log2e), zero accumulators
  if (t < MB) {
    b2[t] = -(log2f(q[t]) + COFF * LOG2E);
    ps[t] = 0.0f;
    cnt[t] = 0.0f;
    if (t == 0) out[0] = 0.0f;
  }
}

// ---- fused GEMM + masked fixed-offset exp-sum + id-match count ----
// Exact R6 champion structure (52.4us): 2-phase dbuf, 4 waves x 32 rows,
// BN=64, register idv/bv prefetch. Added: crun accumulates (idj==idr) so
// finalize gets per-row match counts without a histogram.
__global__ __launch_bounds__(256, 2) void fused_kernel(
    const unsigned short* __restrict__ Abf,
    const unsigned short* __restrict__ Bbf,
    const int* __restrict__ ids,
    const float* __restrict__ b2,
    float* __restrict__ ps, float* __restrict__ cnt) {
  const int slab = blockIdx.y;
  const int tid = threadIdx.x;
  const int wave = tid >> 6;
  const int lane = tid & 63;
  const int quad = lane >> 4;
  const int lpos = lane & 15;
  const int rowbase = blockIdx.x * BM + wave * 32;
  const int colbase = slab * SLAB;

  // Fragment-ordered B staging, DOUBLE buffered: cell c = ((ct*8+kb)*4+quad)*16+lpos
  // holds B[col = ct*16+lpos][k = kb*32+quad*8 .. +8). Linear in c == tid + s8*256,
  // matching global_load_lds's uniform-base+lane*16 dest. Frag reads wave-linear
  // (lane i -> byte 16*i) => conflict-free ds_read_b128.
  __shared__ unsigned short Bs[2][2048 * 8];   // 2 x 32 KB

  // A fragments resident: wave owns rows [rowbase, rowbase+32)
  bf16x8 afrag[2][8];
  #pragma unroll
  for (int rt = 0; rt < 2; ++rt)
    #pragma unroll
    for (int kb = 0; kb < 8; ++kb)
      afrag[rt][kb] = *(const bf16x8*)(Abf + (rowbase + rt * 16 + lpos) * KD + kb * 32 + quad * 8);

  // chunk-invariant staging addresses (advance global side by chunk*BN*KD)
  const unsigned short* gsrc[8];
  int ldso[8];                               // short-offset within one buffer
  #pragma unroll
  for (int s8 = 0; s8 < 8; ++s8) {
    int c = tid + s8 * 256;
    int lp = c & 15, qd = (c >> 4) & 3, kb = (c >> 6) & 7, ct = c >> 9;
    gsrc[s8] = Bbf + (colbase + ct * 16 + lp) * KD + kb * 32 + qd * 8;
    ldso[s8] = c * 8;
  }

  int idr[2][4];
  float srun[2][4];
  float crun[2][4];
  #pragma unroll
  for (int rt = 0; rt < 2; ++rt)
    #pragma unroll
    for (int r = 0; r < 4; ++r) {
      idr[rt][r] = ids[rowbase + rt * 16 + quad * 4 + r];
      srun[rt][r] = 0.0f;
      crun[rt][r] = 0.0f;
    }

  // Prologue: prefetch ids/b2 + B-tile for chunk 0
  int idv[2][4];
  float bv[2][4];
  #pragma unroll
  for (int ct = 0; ct < 4; ++ct) {
    idv[0][ct] = ids[colbase + ct * 16 + lpos];
    bv[0][ct]  = b2 [colbase + ct * 16 + lpos];
  }
  #pragma unroll
  for (int s8 = 0; s8 < 8; ++s8)
    GLOAD_LDS16(gsrc[s8], &Bs[0][0] + ldso[s8]);
  __syncthreads();                           // drains vmcnt(0): chunk 0 ready

  // Per iteration: issue next-chunk ids/b2 loads FIRST (vmcnt retires before
  // DMAs'), then next-chunk DMA, then compute current chunk from regs+LDS only.
  // End-of-body __syncthreads() drains the prefetch under the MFMA+exp phase.
#define FUSED_BODY(T, CUR)                                                     \
  {                                                                            \
    const int nxt = (T) + 1;                                                   \
    if (nxt < NCHUNK) {                                                        \
      _Pragma("unroll")                                                        \
      for (int ct = 0; ct < 4; ++ct) {                                         \
        idv[(CUR) ^ 1][ct] = ids[colbase + nxt * BN + ct * 16 + lpos];         \
        bv[(CUR) ^ 1][ct]  = b2 [colbase + nxt * BN + ct * 16 + lpos];         \
      }                                                                        \
      _Pragma("unroll")                                                        \
      for (int s8 = 0; s8 < 8; ++s8)                                           \
        GLOAD_LDS16(gsrc[s8] + nxt * (BN * KD), &Bs[(CUR) ^ 1][0] + ldso[s8]); \
    }                                                                          \
    _Pragma("unroll")                                                          \
    for (int ct = 0; ct < 4; ++ct) {                                           \
      const unsigned short* bp = &Bs[CUR][0] + (ct * 512 + quad * 16 + lpos) * 8; \
      bf16x8 bfrag[8];                                                         \
      _Pragma("unroll")                                                        \
      for (int kb = 0; kb < 8; ++kb)                                           \
        bfrag[kb] = *(const bf16x8*)(bp + kb * 512);                           \
      const int idj = idv[CUR][ct];                                            \
      const float bj = bv[CUR][ct];                                            \
      _Pragma("unroll")                                                        \
      for (int rt = 0; rt < 2; ++rt) {                                         \
        f32x4 acc = {0.0f, 0.0f, 0.0f, 0.0f};                                  \
        _Pragma("unroll")                                                      \
        for (int kb = 0; kb < 8; ++kb)                                         \
          acc = __builtin_amdgcn_mfma_f32_16x16x32_bf16(afrag[rt][kb], bfrag[kb], acc, 0, 0, 0); \
        _Pragma("unroll")                                                      \
        for (int r = 0; r < 4; ++r) {                                          \
          const bool eq = (idj == idr[rt][r]);                                 \
          const float e = fast_exp2(__builtin_fmaf(acc[r], LOG2E, bj));        \
          srun[rt][r] += eq ? 0.0f : e;                                        \
          crun[rt][r] += eq ? 1.0f : 0.0f;                                     \
        }                                                                      \
      }                                                                        \
    }                                                                          \
    __syncthreads();                                                           \
  }

  for (int t2 = 0; t2 < NCHUNK; t2 += 2) {
    FUSED_BODY(t2, 0)
    FUSED_BODY(t2 + 1, 1)
  }
#undef FUSED_BODY

  // sum across the 16 lanes of each quad (the 16 columns of the frag)
  #pragma unroll
  for (int rt = 0; rt < 2; ++rt)
    #pragma unroll
    for (int r = 0; r < 4; ++r) {
      float v = srun[rt][r];
      float c = crun[rt][r];
      #pragma unroll
      for (int off = 1; off < 16; off <<= 1) {
        v += __shfl_xor(v, off, 64);
        c += __shfl_xor(c, off, 64);
      }
      if (lpos == 0) {
        atomicAdd(&ps[rowbase + rt * 16 + quad * 4 + r], v);
        atomicAdd(&cnt[rowbase + rt * 16 + quad * 4 + r], c);
      }
    }
}

// ---- finalize: per-row loss, mean ----
__global__ __launch_bounds__(256) void finalize_kernel(
    const float* __restrict__ ps, const float* __restrict__ pos,
    const float* __restrict__ q, const float* __restrict__ cnt,
    float* __restrict__ out) {
  int i = blockIdx.x * 256 + threadIdx.x;   // 32 blocks -> 8192 threads
  const float s = ps[i];
  const float nm = (float)MB - cnt[i];      // n_miss = MB - #matches (count is exact in f32)
  // log S_i = log(s) + C + log(1-q_i) - log(n_miss)
  const float z = logf(s) + COFF + logf(1.0f - q[i]) - logf(nm);
  const float p = pos[i];
  const float hi = fmaxf(p, z), lo = fminf(p, z);
  float loss = -p + hi + log1pf(__expf(lo - hi));

  #pragma unroll
  for (int off = 32; off; off >>= 1) loss += __shfl_down(loss, off, 64);
  __shared__ float red[4];
  if ((threadIdx.x & 63) == 0) red[threadIdx.x >> 6] = loss;
  __syncthreads();
  if (threadIdx.x == 0) {
    float t = red[0] + red[1] + red[2] + red[3];
    atomicAdd(out, t * (1.0f / (float)MB));
  }
}

extern "C" void kernel_launch(void* const* d_in, const int* in_sizes, int n_in,
                              void* d_out, int out_size, void* d_ws, size_t ws_size,
                              hipStream_t stream) {
  (void)in_sizes; (void)n_in; (void)out_size; (void)ws_size;
  const float* input_emb  = (const float*)d_in[0];
  const float* target_emb = (const float*)d_in[1];
  const int*   target_ids = (const int*)d_in[2];
  const float* q_probas   = (const float*)d_in[3];
  float* out = (float*)d_out;

  char* ws = (char*)d_ws;
  unsigned short* Abf = (unsigned short*)(ws);                    // 4 MB
  unsigned short* Bbf = (unsigned short*)(ws + (4u << 20));       // 4 MB
  float* b2   = (float*)(ws + (8u << 20));                        // 32 KB
  float* pos  = (float*)(ws + (8u << 20) + 32768);                // 32 KB
  float* ps   = (float*)(ws + (8u << 20) + 65536);                // 32 KB
  float* cnt  = (float*)(ws + (8u << 20) + 98304);                // 32 KB

  prep_kernel<<<2048, 256, 0, stream>>>(input_emb, target_emb, q_probas,
                                        Abf, Bbf, pos, b2, ps, cnt, out);
  fused_kernel<<<dim3(MB / BM, NSPLIT), 256, 0, stream>>>(Abf, Bbf, target_ids,
                                                          b2, ps, cnt);
  finalize_kernel<<<32, 256, 0, stream>>>(ps, pos, q_probas, cnt, out);
}

// Round 22
// 115.643 us; speedup vs baseline: 1.6991x; 1.0357x over previous
//
#include <hip/hip_runtime.h>
#include <hip/hip_bf16.h>
#include <stdint.h>

// Problem constants
#define MB 8192     // batch (rows and cols of sim)
#define KD 256      // embedding dim
#define BM 128      // rows per block (4 waves x 32 rows)
#define BN 64       // cols per chunk
#define NSPLIT 8    // column slabs (512 blocks: proven-good L2 behavior)
#define SLAB (MB / NSPLIT)   // 1024 cols per slab
#define NCHUNK (SLAB / BN)   // 16 chunks per slab
#define COFF 104.0f          // fixed exp offset (overflow/underflow-safe)
#define LOG2E 1.44269504088896340736f

typedef __attribute__((ext_vector_type(8))) short bf16x8;
typedef __attribute__((ext_vector_type(4))) float f32x4;

__device__ __forceinline__ unsigned short f2bf(float x) {
  union { float f; uint32_t u; } v; v.f = x;
  uint32_t r = v.u + 0x7fffu + ((v.u >> 16) & 1u);   // RNE
  return (unsigned short)(r >> 16);
}

__device__ __forceinline__ float fast_exp2(float x) {
#if __has_builtin(__builtin_amdgcn_exp2f)
  return __builtin_amdgcn_exp2f(x);
#else
  return exp2f(x);
#endif
}

// async global->LDS DMA, 16B per lane, LDS dest = wave-uniform base + lane*16
#define GLOAD_LDS16(g, l)                                                      \
  __builtin_amdgcn_global_load_lds(                                            \
      (const __attribute__((address_space(1))) void*)(g),                      \
      (__attribute__((address_space(3))) void*)(l), 16, 0, 0)

// ---- prep: fp32->bf16 for A,B + pos_sim + b2 + zero ps/cnt/out ----
__global__ __launch_bounds__(256) void prep_kernel(
    const float* __restrict__ A, const float* __restrict__ B,
    const float* __restrict__ q,
    unsigned short* __restrict__ Abf, unsigned short* __restrict__ Bbf,
    float* __restrict__ pos, float* __restrict__ b2,
    float* __restrict__ ps, float* __restrict__ cnt,
    float* __restrict__ out) {
  int t = blockIdx.x * 256 + threadIdx.x;        // 524288 threads, 1 float4 each
  const float4 a = ((const float4*)A)[t];
  const float4 b = ((const float4*)B)[t];
  ushort4 oa, ob;
  oa.x = f2bf(a.x); oa.y = f2bf(a.y); oa.z = f2bf(a.z); oa.w = f2bf(a.w);
  ob.x = f2bf(b.x); ob.y = f2bf(b.y); ob.z = f2bf(b.z); ob.w = f2bf(b.w);
  ((ushort4*)Abf)[t] = oa;
  ((ushort4*)Bbf)[t] = ob;
  // pos_sim: wave (t>>6) == row, 64 lanes cover KD/4 float4 chunks
  float d = a.x * b.x + a.y * b.y + a.z * b.z + a.w * b.w;
  #pragma unroll
  for (int off = 32; off; off >>= 1) d += __shfl_down(d, off, 64);
  if ((threadIdx.x & 63) == 0) pos[t >> 6] = d;
  // per-row setup: b2 = -(log2 q + C*log2e), zero accumulators
  if (t < MB) {
    b2[t] = -(log2f(q[t]) + COFF * LOG2E);
    ps[t] = 0.0f;
    cnt[t] = 0.0f;
    if (t == 0) out[0] = 0.0f;
  }
}

// ---- fused GEMM + masked fixed-offset exp-sum + id-match count ----
// R21 champion structure with T4 counted-vmcnt pipeline:
//  - ids/b2 slab tables in LDS (prologue-loaded) => in-loop vmem is EXACTLY
//    the 8 staging DMAs per chunk, so vmcnt counts are clean
//  - per chunk: STAGE(T+1); s_waitcnt vmcnt(8) (T's DMAs done, T+1's 8 stay
//    IN FLIGHT); raw s_barrier; compute T; raw s_barrier (no drain).
//    Replaces __syncthreads()'s vmcnt(0) drain -- the m97-documented ~20%
//    stall -- with a 2-chunk-deep DMA pipeline (T4, m218).
__global__ __launch_bounds__(256, 2) void fused_kernel(
    const unsigned short* __restrict__ Abf,
    const unsigned short* __restrict__ Bbf,
    const int* __restrict__ ids,
    const float* __restrict__ b2,
    float* __restrict__ ps, float* __restrict__ cnt) {
  const int slab = blockIdx.y;
  const int tid = threadIdx.x;
  const int wave = tid >> 6;
  const int lane = tid & 63;
  const int quad = lane >> 4;
  const int lpos = lane & 15;
  const int rowbase = blockIdx.x * BM + wave * 32;
  const int colbase = slab * SLAB;

  // Fragment-ordered B staging, DOUBLE buffered: cell c = ((ct*8+kb)*4+quad)*16+lpos
  // holds B[col = ct*16+lpos][k = kb*32+quad*8 .. +8). Linear in c == tid + s8*256,
  // matching global_load_lds's uniform-base+lane*16 dest. Frag reads wave-linear
  // (lane i -> byte 16*i) => conflict-free ds_read_b128.
  __shared__ unsigned short Bs[2][2048 * 8];   // 2 x 32 KB
  __shared__ int   ids_s[SLAB];                // 4 KB (slab-constant)
  __shared__ float b2_s[SLAB];                 // 4 KB (slab-constant)

  // slab tables: 1024 entries, 4 per thread, coalesced 16B loads
  const int4   tiv = ((const int4*)(ids + colbase))[tid];
  const float4 tbv = ((const float4*)(b2 + colbase))[tid];

  // A fragments resident: wave owns rows [rowbase, rowbase+32)
  bf16x8 afrag[2][8];
  #pragma unroll
  for (int rt = 0; rt < 2; ++rt)
    #pragma unroll
    for (int kb = 0; kb < 8; ++kb)
      afrag[rt][kb] = *(const bf16x8*)(Abf + (rowbase + rt * 16 + lpos) * KD + kb * 32 + quad * 8);

  // chunk-invariant staging addresses (advance global side by chunk*BN*KD)
  const unsigned short* gsrc[8];
  int ldso[8];                               // short-offset within one buffer
  #pragma unroll
  for (int s8 = 0; s8 < 8; ++s8) {
    int c = tid + s8 * 256;
    int lp = c & 15, qd = (c >> 4) & 3, kb = (c >> 6) & 7, ct = c >> 9;
    gsrc[s8] = Bbf + (colbase + ct * 16 + lp) * KD + kb * 32 + qd * 8;
    ldso[s8] = c * 8;
  }

#define STAGE(T, BUF)                                                          \
  _Pragma("unroll")                                                            \
  for (int s8 = 0; s8 < 8; ++s8)                                               \
    GLOAD_LDS16(gsrc[s8] + (T) * (BN * KD), &Bs[BUF][0] + ldso[s8]);

  int idr[2][4];
  float srun[2][4];
  float crun[2][4];
  #pragma unroll
  for (int rt = 0; rt < 2; ++rt)
    #pragma unroll
    for (int r = 0; r < 4; ++r) {
      idr[rt][r] = ids[rowbase + rt * 16 + quad * 4 + r];
      srun[rt][r] = 0.0f;
      crun[rt][r] = 0.0f;
    }

  // Prologue: stage chunk 0, park slab tables in LDS, full drain barrier.
  STAGE(0, 0)
  ((int4*)ids_s)[tid] = tiv;
  ((float4*)b2_s)[tid] = tbv;
  __syncthreads();                           // chunk 0 + tables ready

  // Counted-vmcnt 2-phase loop. Per wave the ONLY in-loop vmem ops are the
  // 8 DMAs/chunk: after issuing T+1's 8, vmcnt(8) retires exactly T's 8.
  // Raw barriers (no vmcnt(0) drain) + "memory"/sched fences per rule #18.
#define FUSED_BODY(T, CUR)                                                     \
  {                                                                            \
    const int nxt = (T) + 1;                                                   \
    if (nxt < NCHUNK) {                                                        \
      STAGE(nxt, (CUR) ^ 1)                                                    \
      asm volatile("s_waitcnt vmcnt(8)" ::: "memory");                         \
    } else {                                                                   \
      asm volatile("s_waitcnt vmcnt(0)" ::: "memory");                         \
    }                                                                          \
    __builtin_amdgcn_s_barrier();            /* all waves: chunk T visible */  \
    __builtin_amdgcn_sched_barrier(0);                                         \
    _Pragma("unroll")                                                          \
    for (int ct = 0; ct < 4; ++ct) {                                           \
      const int jloc = (T) * BN + ct * 16 + lpos;                              \
      const int idj = ids_s[jloc];                                             \
      const float bj = b2_s[jloc];                                             \
      const unsigned short* bp = &Bs[CUR][0] + (ct * 512 + quad * 16 + lpos) * 8; \
      bf16x8 bfrag[8];                                                         \
      _Pragma("unroll")                                                        \
      for (int kb = 0; kb < 8; ++kb)                                           \
        bfrag[kb] = *(const bf16x8*)(bp + kb * 512);                           \
      _Pragma("unroll")                                                        \
      for (int rt = 0; rt < 2; ++rt) {                                         \
        f32x4 acc = {0.0f, 0.0f, 0.0f, 0.0f};                                  \
        _Pragma("unroll")                                                      \
        for (int kb = 0; kb < 8; ++kb)                                         \
          acc = __builtin_amdgcn_mfma_f32_16x16x32_bf16(afrag[rt][kb], bfrag[kb], acc, 0, 0, 0); \
        _Pragma("unroll")                                                      \
        for (int r = 0; r < 4; ++r) {                                          \
          const bool eq = (idj == idr[rt][r]);                                 \
          const float e = fast_exp2(__builtin_fmaf(acc[r], LOG2E, bj));        \
          srun[rt][r] += eq ? 0.0f : e;                                        \
          crun[rt][r] += eq ? 1.0f : 0.0f;                                     \
        }                                                                      \
      }                                                                        \
    }                                                                          \
    asm volatile("" ::: "memory");                                             \
    __builtin_amdgcn_s_barrier();            /* Bs[CUR] reads done: safe to */ \
    __builtin_amdgcn_sched_barrier(0);       /* re-stage into CUR next iter */ \
  }

  for (int t2 = 0; t2 < NCHUNK; t2 += 2) {
    FUSED_BODY(t2, 0)
    FUSED_BODY(t2 + 1, 1)
  }
#undef FUSED_BODY
#undef STAGE

  // sum across the 16 lanes of each quad (the 16 columns of the frag)
  #pragma unroll
  for (int rt = 0; rt < 2; ++rt)
    #pragma unroll
    for (int r = 0; r < 4; ++r) {
      float v = srun[rt][r];
      float c = crun[rt][r];
      #pragma unroll
      for (int off = 1; off < 16; off <<= 1) {
        v += __shfl_xor(v, off, 64);
        c += __shfl_xor(c, off, 64);
      }
      if (lpos == 0) {
        atomicAdd(&ps[rowbase + rt * 16 + quad * 4 + r], v);
        atomicAdd(&cnt[rowbase + rt * 16 + quad * 4 + r], c);
      }
    }
}

// ---- finalize: per-row loss, mean ----
__global__ __launch_bounds__(256) void finalize_kernel(
    const float* __restrict__ ps, const float* __restrict__ pos,
    const float* __restrict__ q, const float* __restrict__ cnt,
    float* __restrict__ out) {
  int i = blockIdx.x * 256 + threadIdx.x;   // 32 blocks -> 8192 threads
  const float s = ps[i];
  const float nm = (float)MB - cnt[i];      // n_miss = MB - #matches
  // log S_i = log(s) + C + log(1-q_i) - log(n_miss)
  const float z = logf(s) + COFF + logf(1.0f - q[i]) - logf(nm);
  const float p = pos[i];
  const float hi = fmaxf(p, z), lo = fminf(p, z);
  float loss = -p + hi + log1pf(__expf(lo - hi));

  #pragma unroll
  for (int off = 32; off; off >>= 1) loss += __shfl_down(loss, off, 64);
  __shared__ float red[4];
  if ((threadIdx.x & 63) == 0) red[threadIdx.x >> 6] = loss;
  __syncthreads();
  if (threadIdx.x == 0) {
    float t = red[0] + red[1] + red[2] + red[3];
    atomicAdd(out, t * (1.0f / (float)MB));
  }
}

extern "C" void kernel_launch(void* const* d_in, const int* in_sizes, int n_in,
                              void* d_out, int out_size, void* d_ws, size_t ws_size,
                              hipStream_t stream) {
  (void)in_sizes; (void)n_in; (void)out_size; (void)ws_size;
  const float* input_emb  = (const float*)d_in[0];
  const float* target_emb = (const float*)d_in[1];
  const int*   target_ids = (const int*)d_in[2];
  const float* q_probas   = (const float*)d_in[3];
  float* out = (float*)d_out;

  char* ws = (char*)d_ws;
  unsigned short* Abf = (unsigned short*)(ws);                    // 4 MB
  unsigned short* Bbf = (unsigned short*)(ws + (4u << 20));       // 4 MB
  float* b2   = (float*)(ws + (8u << 20));                        // 32 KB
  float* pos  = (float*)(ws + (8u << 20) + 32768);                // 32 KB
  float* ps   = (float*)(ws + (8u << 20) + 65536);                // 32 KB
  float* cnt  = (float*)(ws + (8u << 20) + 98304);                // 32 KB

  prep_kernel<<<2048, 256, 0, stream>>>(input_emb, target_emb, q_probas,
                                        Abf, Bbf, pos, b2, ps, cnt, out);
  fused_kernel<<<dim3(MB / BM, NSPLIT), 256, 0, stream>>>(Abf, Bbf, target_ids,
                                                          b2, ps, cnt);
  finalize_kernel<<<32, 256, 0, stream>>>(ps, pos, q_probas, cnt, out);
}